// Round 4
// baseline (258.510 us; speedup 1.0000x reference)
//
#include <hip/hip_runtime.h>
#include <math.h>

#define L_ 2
#define BAT_ 32
#define A_ 64
#define B_ 1024
#define D_ 128
#define NBITS_ 1024
#define NW 32                 // u32 words per code (1024 bits)
#define NQROWS (L_*BAT_*A_)   // 4096
#define NDROWS (L_*BAT_*B_)   // 65536
#define NROWS (NQROWS + NDROWS) // 69632
#define NAGRP (NROWS / 16)    // 4352 A-row groups of 16
#define NBGRP (NBITS_ / 16)   // 64 bit groups of 16

#define TM 128                // rows per tile
#define TN 128                // bits per tile
#define NXB (NROWS / TM)      // 544 x-tiles
#define NYB (NBITS_ / TN)     // 8 y-tiles
#define XPX (NXB / 8)         // 68 x-tiles per XCD

typedef __bf16 bf16x8 __attribute__((ext_vector_type(8)));
typedef float  f32x4  __attribute__((ext_vector_type(4)));

// ---- Stage 0: split fp32 -> bf16 hi/lo AND swizzle into MFMA fragment order.
// Per 16-row group: layout [cbi:8][quad:4][col:16][8 bf16] = 4096 bf16 (8 KB).
// Chunk index c = ks*16 + hl*8 + kk*4 + quad maps to source fp32
// k-offset ks*64 + kk*32 + quad*8 (hi if hl=0, lo if hl=1); cbi = c>>2.
__global__ __launch_bounds__(256) void preswz_kernel(
    const float* __restrict__ qe, const float* __restrict__ de,
    const float* __restrict__ r, __bf16* __restrict__ asw,
    __bf16* __restrict__ rsw)
{
    const int g = blockIdx.x;       // 0..4415: A groups then r groups
    const int t = threadIdx.x;
    const int ks = t >> 7, kk = (t >> 6) & 1, quad = (t >> 4) & 3, col = t & 15;

    const float* src;
    __bf16* dst;
    if (g < NAGRP) {
        int row = g * 16 + col;
        src = (row < NQROWS) ? (qe + (size_t)row * D_)
                             : (de + (size_t)(row - NQROWS) * D_);
        dst = asw + (size_t)g * 4096;
    } else {
        int bit = (g - NAGRP) * 16 + col;
        src = r + (size_t)bit * D_;
        dst = rsw + (size_t)(g - NAGRP) * 4096;
    }

    const int ko = ks * 64 + kk * 32 + quad * 8;
    float4 v0 = *(const float4*)(src + ko);
    float4 v1 = *(const float4*)(src + ko + 4);
    bf16x8 hi, lo;
    hi[0] = (__bf16)v0.x; hi[1] = (__bf16)v0.y;
    hi[2] = (__bf16)v0.z; hi[3] = (__bf16)v0.w;
    hi[4] = (__bf16)v1.x; hi[5] = (__bf16)v1.y;
    hi[6] = (__bf16)v1.z; hi[7] = (__bf16)v1.w;
    lo[0] = (__bf16)(v0.x - (float)hi[0]);
    lo[1] = (__bf16)(v0.y - (float)hi[1]);
    lo[2] = (__bf16)(v0.z - (float)hi[2]);
    lo[3] = (__bf16)(v0.w - (float)hi[3]);
    lo[4] = (__bf16)(v1.x - (float)hi[4]);
    lo[5] = (__bf16)(v1.y - (float)hi[5]);
    lo[6] = (__bf16)(v1.z - (float)hi[6]);
    lo[7] = (__bf16)(v1.w - (float)hi[7]);

    const int c_hi = ks * 16 + kk * 4 + quad;   // hl=0
    const int c_lo = c_hi + 8;                  // hl=1
    *(bf16x8*)(dst + (size_t)(c_hi * 16 + col) * 8) = hi;
    *(bf16x8*)(dst + (size_t)(c_lo * 16 + col) * 8) = lo;
}

// ---- Stage 1: LSH sign-hash — PERSISTENT blocks ---------------------------
// R13: grid = 512 blocks exactly (2/CU, all co-resident). Each block owns one
// by (B-tile staged to LDS ONCE) and a strip of 8-9 x-tiles within its XCD.
//  * R12 post-mortem: MfmaUtil pinned ~35% across 3 structures; the invariant
//    is the per-block {prefetch+stage 64KB -> barrier -> compute -> drain}
//    skeleton: ~40-50% of each short block's lifetime is the staging bubble.
//    Persistent blocks amortize stage+barrier over ~8.5 tiles and leave ZERO
//    barriers in the main loop, so waves desync and hide each other's loads.
//  * 64 blocks/XCD = 8 strips x 8 by; same-strip blocks share A via XCD L2
//    (R10's FETCH 102->19.5MB win preserved).
//  * All 8 B-frag ds_read_b128 grouped ahead of 24 MFMAs; depth-1 cross-tile
//    A prefetch; s_setprio(1) around MFMA clusters (waves now phase-diverge).
__global__ __launch_bounds__(512, 4) void hash_kernel(
    const __bf16* __restrict__ asw, const __bf16* __restrict__ rsw,
    unsigned int* __restrict__ codes_t)
{
    __shared__ __align__(16) unsigned char bsh[65536];

    const int t = threadIdx.x;
    const int lane = t & 63;
    const int quad = lane >> 4;       // 0..3
    const int col  = lane & 15;       // 0..15
    const int wv   = __builtin_amdgcn_readfirstlane(t >> 6);  // wave 0..7

    const int bid   = blockIdx.x;     // 0..511
    const int xcd   = bid & 7;        // consecutive blocks round-robin XCDs
    const int sb    = bid >> 3;       // 0..63 within XCD
    const int by    = sb & 7;
    const int strip = sb >> 3;        // 0..7
    const int s0 = (strip * XPX) >> 3;        // floor(strip*8.5)
    const int s1 = ((strip + 1) * XPX) >> 3;
    const int bx0 = xcd * XPX + s0;
    const int ntiles = s1 - s0;       // 8 or 9

    const int wrow = (wv >> 1) * 32;  // 4 wave-rows of 32
    const int half = wv & 1;          // 2 wave-cols of 64 bits

    // A frag (ti, cbi) at pointer P: P + (ti*8 + cbi)*512 elems
    const __bf16* abase = asw + ((size_t)((bx0 * TM + wrow) >> 4)) * 4096
                              + (size_t)lane * 8;
#define ALOAD(P, ti, cbi) (*(const bf16x8*)((P) + ((ti) * 8 + (cbi)) * 512))
#define TILE_STRIDE 32768   /* 8 groups * 4096 elems */

    // B frag (tj, cbi) from LDS: half*32768 + tj*8192 + cbi*1024 + lane*16 B
    const unsigned char* bbase = bsh + half * 32768 + lane * 16;
#define BLOAD(tj, cbi) (*(const bf16x8*)(bbase + (tj) * 8192 + (cbi) * 1024))

    // Prefetch tile-0 iter-0 A frags; they complete by the staging barrier.
    bf16x8 xh0 = ALOAD(abase, 0, 0), xh1 = ALOAD(abase, 1, 0);
    bf16x8 xl0 = ALOAD(abase, 0, 2), xl1 = ALOAD(abase, 1, 2);
    bf16x8 yh0, yh1, yl0, yl1;

    // Stage this block's B tile (rsw + by*64KB, contiguous) into LDS, once.
    {
        const char* bsrc = (const char*)rsw + (size_t)by * 65536 + (size_t)t * 16;
        #pragma unroll
        for (int i = 0; i < 8; ++i)
            __builtin_amdgcn_global_load_lds(
                (const __attribute__((address_space(1))) unsigned int*)(bsrc + i * 8192),
                (__attribute__((address_space(3))) unsigned int*)(bsh + i * 8192 + t * 16),
                16, 0, 0);
    }
    __syncthreads();

#define MFMA __builtin_amdgcn_mfma_f32_16x16x32_bf16
#define BATCH(A0, A1, B0, B1, B2, B3)                       \
    acc[0][0] = MFMA(A0, B0, acc[0][0], 0, 0, 0);           \
    acc[0][1] = MFMA(A0, B1, acc[0][1], 0, 0, 0);           \
    acc[0][2] = MFMA(A0, B2, acc[0][2], 0, 0, 0);           \
    acc[1][0] = MFMA(A1, B0, acc[1][0], 0, 0, 0);           \
    acc[1][1] = MFMA(A1, B1, acc[1][1], 0, 0, 0);           \
    acc[0][2] = acc[0][2];                                  \
    acc[0][3] = MFMA(A0, B3, acc[0][3], 0, 0, 0);           \
    acc[1][2] = MFMA(A1, B2, acc[1][2], 0, 0, 0);           \
    acc[1][3] = MFMA(A1, B3, acc[1][3], 0, 0, 0);

// One (ks,kk) step: prefetch next A frags from PBASE, group ALL 8 B ds_reads,
// then 24 MFMAs under setprio. hh/lh use group CH, hl uses CH+2.
#define ITER(CH, cH0, cH1, cL0, cL1, PBASE, NH, nH0, nH1, nL0, nL1)     \
    {                                                                    \
        nH0 = ALOAD(PBASE, 0, NH);       nH1 = ALOAD(PBASE, 1, NH);      \
        nL0 = ALOAD(PBASE, 0, (NH) + 2); nL1 = ALOAD(PBASE, 1, (NH) + 2);\
        bf16x8 b0 = BLOAD(0, CH), b1 = BLOAD(1, CH),                     \
               b2 = BLOAD(2, CH), b3 = BLOAD(3, CH);                     \
        bf16x8 c0 = BLOAD(0, (CH) + 2), c1 = BLOAD(1, (CH) + 2),         \
               c2 = BLOAD(2, (CH) + 2), c3 = BLOAD(3, (CH) + 2);         \
        __builtin_amdgcn_s_setprio(1);                                   \
        BATCH(cH0, cH1, b0, b1, b2, b3)      /* hi*hi */                 \
        BATCH(cL0, cL1, b0, b1, b2, b3)      /* lo*hi */                 \
        BATCH(cH0, cH1, c0, c1, c2, c3)      /* hi*lo */                 \
        __builtin_amdgcn_s_setprio(0);                                   \
    }

    for (int i = 0; i < ntiles; ++i) {
        f32x4 acc[2][4];
        #pragma unroll
        for (int ti = 0; ti < 2; ++ti)
            #pragma unroll
            for (int tj = 0; tj < 4; ++tj)
                acc[ti][tj] = (f32x4){0.f, 0.f, 0.f, 0.f};

        const __bf16* anext = (i + 1 < ntiles) ? (abase + TILE_STRIDE) : abase;

        // cbi_h sequence over (ks,kk) = (0,0),(0,1),(1,0),(1,1): {0,1,4,5}
        ITER(0, xh0, xh1, xl0, xl1, abase, 1, yh0, yh1, yl0, yl1)
        ITER(1, yh0, yh1, yl0, yl1, abase, 4, xh0, xh1, xl0, xl1)
        ITER(4, xh0, xh1, xl0, xl1, abase, 5, yh0, yh1, yl0, yl1)
        ITER(5, yh0, yh1, yl0, yl1, anext, 0, xh0, xh1, xl0, xl1)

        // Sign-pack via ballot; C/D layout (m89): col=lane&15, row=quad*4+reg.
        // TRANSPOSED store: codes_t[word][row]. No barrier -> overlaps the
        // next tile's A prefetch / B ds_reads on other waves.
        const int row0 = (bx0 + i) * TM;
        #pragma unroll
        for (int ti = 0; ti < 2; ++ti) {
            #pragma unroll
            for (int rg = 0; rg < 4; ++rg) {
                unsigned long long b[4];
                #pragma unroll
                for (int tj = 0; tj < 4; ++tj)
                    b[tj] = __ballot(acc[ti][tj][rg] > 0.f);
                if (col < 2) {
                    const int w = col;
                    unsigned int lo16 = (unsigned int)(b[2 * w]     >> (16 * quad)) & 0xFFFFu;
                    unsigned int hi16 = (unsigned int)(b[2 * w + 1] >> (16 * quad)) & 0xFFFFu;
                    const int row = row0 + wrow + ti * 16 + quad * 4 + rg;
                    const int wg  = by * 4 + half * 2 + w;
                    codes_t[(size_t)wg * NROWS + row] = lo16 | (hi16 << 16);
                }
            }
        }
        abase = anext;
    }

#undef ITER
#undef BATCH
#undef MFMA
#undef BLOAD
#undef ALOAD

}

// ---- Stage 2: Hamming -> cos (HW v_cos) -> mask -> out ---------------------
// UNCHANGED. grid: 2048 blocks, 8 blocks/CU.
__global__ __launch_bounds__(256) void simmat_kernel(
    const unsigned int* __restrict__ codes_t,
    const int* __restrict__ qtok, const int* __restrict__ dtok,
    float* __restrict__ out)
{
    __shared__ unsigned int qc[8 * 36];

    const int blk  = blockIdx.x;
    const int ct   = blk & 3;
    const int asub = (blk >> 2) & 7;
    const int b    = (blk >> 5) & 31;
    const int l    = blk >> 10;
    const int t    = threadIdx.x;

    const int a0 = asub * 8;
    const int qrow0 = (l * BAT_ + b) * A_ + a0;
    if (t < 256) {
        int w = t >> 3, a = t & 7;
        qc[a * 36 + w] = codes_t[(size_t)w * NROWS + qrow0 + a];
    }
    __syncthreads();

    const int c = ct * 256 + t;
    const size_t drow = (size_t)NQROWS + (size_t)(l * BAT_ + b) * B_ + c;
    unsigned int dc[NW];
    #pragma unroll
    for (int w = 0; w < NW; ++w) dc[w] = codes_t[(size_t)w * NROWS + drow];
    const float dm = (dtok[b * B_ + c] != 0) ? 1.f : 0.f;

    float* obase = out + ((size_t)((b * L_ + l) * A_ + a0)) * B_ + c;
    #pragma unroll
    for (int ai = 0; ai < 8; ++ai) {
        int ham = 0;
        #pragma unroll
        for (int m = 0; m < 8; ++m) {
            uint4 qv = *(const uint4*)(&qc[ai * 36 + m * 4]);
            ham += __popc(qv.x ^ dc[4 * m])     + __popc(qv.y ^ dc[4 * m + 1])
                 + __popc(qv.z ^ dc[4 * m + 2]) + __popc(qv.w ^ dc[4 * m + 3]);
        }
        const float qmv = (qtok[b * A_ + a0 + ai] != 0) ? 1.f : 0.f;
        float sim = __cosf((float)M_PI / (float)NBITS_ * (float)ham);
        obase[(size_t)ai * B_] = sim * (qmv * dm);
    }
}

extern "C" void kernel_launch(void* const* d_in, const int* in_sizes, int n_in,
                              void* d_out, int out_size, void* d_ws, size_t ws_size,
                              hipStream_t stream) {
    const float* qe  = (const float*)d_in[0];  // [L,BAT,A,D]
    const float* de  = (const float*)d_in[1];  // [L,BAT,B,D]
    const int* qtok  = (const int*)d_in[2];    // [BAT,A]
    const int* dtok  = (const int*)d_in[3];    // [BAT,B]
    const float* r   = (const float*)d_in[4];  // [NBITS,D]
    float* out = (float*)d_out;                // [BAT,L,A,B] fp32

    // ws: [0, 8.5MB) codes_t | [8.5, 9.0MB) rsw | [9.0MB, +34MB) asw
    unsigned int* codes_t = (unsigned int*)d_ws;                    // 8912896 B
    __bf16* rsw = (__bf16*)((char*)d_ws + 8912896);                 // 524288 B
    __bf16* asw = (__bf16*)((char*)d_ws + 8912896 + 524288);        // 35651584 B

    preswz_kernel<<<NAGRP + NBGRP, 256, 0, stream>>>(qe, de, r, asw, rsw);
    hash_kernel<<<512, 512, 0, stream>>>(asw, rsw, codes_t);
    simmat_kernel<<<L_ * BAT_ * 8 * 4, 256, 0, stream>>>(codes_t, qtok, dtok, out);
}

// Round 5
// 155.771 us; speedup vs baseline: 1.6596x; 1.6596x over previous
//
#include <hip/hip_runtime.h>
#include <math.h>

#define L_ 2
#define BAT_ 32
#define A_ 64
#define B_ 1024
#define D_ 128
#define NBITS_ 1024
#define NW 32                 // u32 words per code (1024 bits)
#define NQROWS (L_*BAT_*A_)   // 4096
#define NDROWS (L_*BAT_*B_)   // 65536
#define NROWS (NQROWS + NDROWS) // 69632
#define NAGRP (NROWS / 16)    // 4352 A-row groups of 16
#define NBGRP (NBITS_ / 16)   // 64 bit groups of 16

#define TM 128                // rows per tile
#define TN 128                // bits per tile
#define NXB (NROWS / TM)      // 544 x-tiles
#define NYB (NBITS_ / TN)     // 8 y-tiles
#define XPX (NXB / 8)         // 68 x-tiles per XCD
#define NTPB 4                // x-tiles per block (68 % 4 == 0)

typedef __bf16 bf16x8 __attribute__((ext_vector_type(8)));
typedef float  f32x4  __attribute__((ext_vector_type(4)));

// ---- Stage 0: split fp32 -> bf16 hi/lo AND swizzle into MFMA fragment order.
// Per 16-row group: layout [cbi:8][quad:4][col:16][8 bf16] = 4096 bf16 (8 KB).
// Chunk index c = ks*16 + hl*8 + kk*4 + quad maps to source fp32
// k-offset ks*64 + kk*32 + quad*8 (hi if hl=0, lo if hl=1); cbi = c>>2.
__global__ __launch_bounds__(256) void preswz_kernel(
    const float* __restrict__ qe, const float* __restrict__ de,
    const float* __restrict__ r, __bf16* __restrict__ asw,
    __bf16* __restrict__ rsw)
{
    const int g = blockIdx.x;       // 0..4415: A groups then r groups
    const int t = threadIdx.x;
    const int ks = t >> 7, kk = (t >> 6) & 1, quad = (t >> 4) & 3, col = t & 15;

    const float* src;
    __bf16* dst;
    if (g < NAGRP) {
        int row = g * 16 + col;
        src = (row < NQROWS) ? (qe + (size_t)row * D_)
                             : (de + (size_t)(row - NQROWS) * D_);
        dst = asw + (size_t)g * 4096;
    } else {
        int bit = (g - NAGRP) * 16 + col;
        src = r + (size_t)bit * D_;
        dst = rsw + (size_t)(g - NAGRP) * 4096;
    }

    const int ko = ks * 64 + kk * 32 + quad * 8;
    float4 v0 = *(const float4*)(src + ko);
    float4 v1 = *(const float4*)(src + ko + 4);
    bf16x8 hi, lo;
    hi[0] = (__bf16)v0.x; hi[1] = (__bf16)v0.y;
    hi[2] = (__bf16)v0.z; hi[3] = (__bf16)v0.w;
    hi[4] = (__bf16)v1.x; hi[5] = (__bf16)v1.y;
    hi[6] = (__bf16)v1.z; hi[7] = (__bf16)v1.w;
    lo[0] = (__bf16)(v0.x - (float)hi[0]);
    lo[1] = (__bf16)(v0.y - (float)hi[1]);
    lo[2] = (__bf16)(v0.z - (float)hi[2]);
    lo[3] = (__bf16)(v0.w - (float)hi[3]);
    lo[4] = (__bf16)(v1.x - (float)hi[4]);
    lo[5] = (__bf16)(v1.y - (float)hi[5]);
    lo[6] = (__bf16)(v1.z - (float)hi[6]);
    lo[7] = (__bf16)(v1.w - (float)hi[7]);

    const int c_hi = ks * 16 + kk * 4 + quad;   // hl=0
    const int c_lo = c_hi + 8;                  // hl=1
    *(bf16x8*)(dst + (size_t)(c_hi * 16 + col) * 8) = hi;
    *(bf16x8*)(dst + (size_t)(c_lo * 16 + col) * 8) = lo;
}

// ---- Stage 1: LSH sign-hash — R3 structure + 4-tile amortization ----------
// R14 = R3 (verified 61.4us, VGPR=56, 0 spill) with ONE change: each block
// processes 4 consecutive x-tiles against its once-staged 64KB B tile.
//  * R4 post-mortem: persistent version spilled to scratch (WRITE 8.7->111MB)
//    and thrashed XCD L2 with 512 desynced strips (FETCH 19.5->428MB).
//    This version keeps R3's exact inner ITER/BATCH codegen; the only new
//    register traffic is the 4th ITER's prefetch slot pointing at the next
//    tile's group-0 (same footprint as ITERs 1-3). No setprio, no strips.
//  * Staging bubble (the ~35% per-block overhead invariant across R1-R3)
//    is amortized 4x; NO barriers inside the tile loop, so waves desync
//    and cover each other's ds_read/A-load latency.
//  * Grid 1088: bid&7 = XCD; consecutive s -> all 8 by-blocks of one A-quad
//    co-resident per XCD (A-quad 1MB + B 512KB fits 4MB L2).
__global__ __launch_bounds__(512, 4) void hash_kernel(
    const __bf16* __restrict__ asw, const __bf16* __restrict__ rsw,
    unsigned int* __restrict__ codes_t)
{
    __shared__ __align__(16) unsigned char bsh[65536];

    const int t = threadIdx.x;
    const int lane = t & 63;
    const int quad = lane >> 4;       // 0..3
    const int col  = lane & 15;       // 0..15
    const int wv   = __builtin_amdgcn_readfirstlane(t >> 6);  // wave 0..7

    const int bid = blockIdx.x;       // 0..1087
    const int xcd = bid & 7;
    const int s   = bid >> 3;         // 0..135
    const int by  = s & 7;
    const int xq  = s >> 3;           // 0..16
    const int bx0 = xcd * XPX + xq * NTPB;

    const int wrow = (wv >> 1) * 32;  // 4 wave-rows of 32
    const int half = wv & 1;          // 2 wave-cols of 64 bits

    // A frag (ti, cbi) at pointer P: P + (ti*8 + cbi)*512 elems
    const __bf16* abase = asw + ((size_t)((bx0 * TM + wrow) >> 4)) * 4096
                              + (size_t)lane * 8;
#define ALOAD(P, ti, cbi) (*(const bf16x8*)((P) + ((ti) * 8 + (cbi)) * 512))
#define TILE_STRIDE 32768   /* 8 groups * 4096 elems */

    // B frag (tj, cbi) from LDS: half*32768 + tj*8192 + cbi*1024 + lane*16 B
    const unsigned char* bbase = bsh + half * 32768 + lane * 16;
#define BLOAD(tj, cbi) (*(const bf16x8*)(bbase + (tj) * 8192 + (cbi) * 1024))

    // Prefetch tile-0 iter-0 A frags; they complete by the staging barrier.
    bf16x8 xh0 = ALOAD(abase, 0, 0), xh1 = ALOAD(abase, 1, 0);
    bf16x8 xl0 = ALOAD(abase, 0, 2), xl1 = ALOAD(abase, 1, 2);
    bf16x8 yh0, yh1, yl0, yl1;

    // Stage this block's B tile (rsw + by*64KB, contiguous) into LDS, once.
    {
        const char* bsrc = (const char*)rsw + (size_t)by * 65536 + (size_t)t * 16;
        #pragma unroll
        for (int i = 0; i < 8; ++i)
            __builtin_amdgcn_global_load_lds(
                (const __attribute__((address_space(1))) unsigned int*)(bsrc + i * 8192),
                (__attribute__((address_space(3))) unsigned int*)(bsh + i * 8192 + t * 16),
                16, 0, 0);
    }
    __syncthreads();

#define MFMA __builtin_amdgcn_mfma_f32_16x16x32_bf16
#define BATCH(A0, A1, B0, B1, B2, B3)                       \
    acc[0][0] = MFMA(A0, B0, acc[0][0], 0, 0, 0);           \
    acc[0][1] = MFMA(A0, B1, acc[0][1], 0, 0, 0);           \
    acc[0][2] = MFMA(A0, B2, acc[0][2], 0, 0, 0);           \
    acc[0][3] = MFMA(A0, B3, acc[0][3], 0, 0, 0);           \
    acc[1][0] = MFMA(A1, B0, acc[1][0], 0, 0, 0);           \
    acc[1][1] = MFMA(A1, B1, acc[1][1], 0, 0, 0);           \
    acc[1][2] = MFMA(A1, B2, acc[1][2], 0, 0, 0);           \
    acc[1][3] = MFMA(A1, B3, acc[1][3], 0, 0, 0);

// One (ks,kk) step: prefetch next A frag group from PBASE, then hh/lh on the
// CH B-group, then hi*lo on the CH+2 B-group. Identical shape to R3's ITER.
#define ITER(CH, cH0, cH1, cL0, cL1, PBASE, NH, nH0, nH1, nL0, nL1)     \
    {                                                                    \
        nH0 = ALOAD(PBASE, 0, NH);       nH1 = ALOAD(PBASE, 1, NH);      \
        nL0 = ALOAD(PBASE, 0, (NH) + 2); nL1 = ALOAD(PBASE, 1, (NH) + 2);\
        bf16x8 b0 = BLOAD(0, CH), b1 = BLOAD(1, CH),                     \
               b2 = BLOAD(2, CH), b3 = BLOAD(3, CH);                     \
        BATCH(cH0, cH1, b0, b1, b2, b3)      /* hi*hi */                 \
        BATCH(cL0, cL1, b0, b1, b2, b3)      /* lo*hi */                 \
        b0 = BLOAD(0, (CH) + 2); b1 = BLOAD(1, (CH) + 2);                \
        b2 = BLOAD(2, (CH) + 2); b3 = BLOAD(3, (CH) + 2);                \
        BATCH(cH0, cH1, b0, b1, b2, b3)      /* hi*lo */                 \
    }

    #pragma unroll
    for (int i = 0; i < NTPB; ++i) {
        const __bf16* ab = abase + (size_t)i * TILE_STRIDE;
        const __bf16* an = (i + 1 < NTPB) ? (ab + TILE_STRIDE) : ab;

        f32x4 acc[2][4];
        #pragma unroll
        for (int ti = 0; ti < 2; ++ti)
            #pragma unroll
            for (int tj = 0; tj < 4; ++tj)
                acc[ti][tj] = (f32x4){0.f, 0.f, 0.f, 0.f};

        // cbi_h sequence over (ks,kk) = (0,0),(0,1),(1,0),(1,1): {0,1,4,5}
        ITER(0, xh0, xh1, xl0, xl1, ab, 1, yh0, yh1, yl0, yl1)
        ITER(1, yh0, yh1, yl0, yl1, ab, 4, xh0, xh1, xl0, xl1)
        ITER(4, xh0, xh1, xl0, xl1, ab, 5, yh0, yh1, yl0, yl1)
        ITER(5, yh0, yh1, yl0, yl1, an, 0, xh0, xh1, xl0, xl1)

        // Sign-pack via ballot; C/D layout (m89): col=lane&15, row=quad*4+reg.
        // TRANSPOSED store: codes_t[word][row]. No barrier after -> epilogue
        // overlaps the next tile's prefetched A loads.
        const int row0 = (bx0 + i) * TM;
        #pragma unroll
        for (int ti = 0; ti < 2; ++ti) {
            #pragma unroll
            for (int rg = 0; rg < 4; ++rg) {
                unsigned long long b[4];
                #pragma unroll
                for (int tj = 0; tj < 4; ++tj)
                    b[tj] = __ballot(acc[ti][tj][rg] > 0.f);
                if (col < 2) {
                    const int w = col;
                    unsigned int lo16 = (unsigned int)(b[2 * w]     >> (16 * quad)) & 0xFFFFu;
                    unsigned int hi16 = (unsigned int)(b[2 * w + 1] >> (16 * quad)) & 0xFFFFu;
                    const int row = row0 + wrow + ti * 16 + quad * 4 + rg;
                    const int wg  = by * 4 + half * 2 + w;
                    codes_t[(size_t)wg * NROWS + row] = lo16 | (hi16 << 16);
                }
            }
        }
    }

#undef ITER
#undef BATCH
#undef MFMA
#undef BLOAD
#undef ALOAD
}

// ---- Stage 2: Hamming -> cos (HW v_cos) -> mask -> out ---------------------
// UNCHANGED. grid: 2048 blocks, 8 blocks/CU.
__global__ __launch_bounds__(256) void simmat_kernel(
    const unsigned int* __restrict__ codes_t,
    const int* __restrict__ qtok, const int* __restrict__ dtok,
    float* __restrict__ out)
{
    __shared__ unsigned int qc[8 * 36];

    const int blk  = blockIdx.x;
    const int ct   = blk & 3;
    const int asub = (blk >> 2) & 7;
    const int b    = (blk >> 5) & 31;
    const int l    = blk >> 10;
    const int t    = threadIdx.x;

    const int a0 = asub * 8;
    const int qrow0 = (l * BAT_ + b) * A_ + a0;
    if (t < 256) {
        int w = t >> 3, a = t & 7;
        qc[a * 36 + w] = codes_t[(size_t)w * NROWS + qrow0 + a];
    }
    __syncthreads();

    const int c = ct * 256 + t;
    const size_t drow = (size_t)NQROWS + (size_t)(l * BAT_ + b) * B_ + c;
    unsigned int dc[NW];
    #pragma unroll
    for (int w = 0; w < NW; ++w) dc[w] = codes_t[(size_t)w * NROWS + drow];
    const float dm = (dtok[b * B_ + c] != 0) ? 1.f : 0.f;

    float* obase = out + ((size_t)((b * L_ + l) * A_ + a0)) * B_ + c;
    #pragma unroll
    for (int ai = 0; ai < 8; ++ai) {
        int ham = 0;
        #pragma unroll
        for (int m = 0; m < 8; ++m) {
            uint4 qv = *(const uint4*)(&qc[ai * 36 + m * 4]);
            ham += __popc(qv.x ^ dc[4 * m])     + __popc(qv.y ^ dc[4 * m + 1])
                 + __popc(qv.z ^ dc[4 * m + 2]) + __popc(qv.w ^ dc[4 * m + 3]);
        }
        const float qmv = (qtok[b * A_ + a0 + ai] != 0) ? 1.f : 0.f;
        float sim = __cosf((float)M_PI / (float)NBITS_ * (float)ham);
        obase[(size_t)ai * B_] = sim * (qmv * dm);
    }
}

extern "C" void kernel_launch(void* const* d_in, const int* in_sizes, int n_in,
                              void* d_out, int out_size, void* d_ws, size_t ws_size,
                              hipStream_t stream) {
    const float* qe  = (const float*)d_in[0];  // [L,BAT,A,D]
    const float* de  = (const float*)d_in[1];  // [L,BAT,B,D]
    const int* qtok  = (const int*)d_in[2];    // [BAT,A]
    const int* dtok  = (const int*)d_in[3];    // [BAT,B]
    const float* r   = (const float*)d_in[4];  // [NBITS,D]
    float* out = (float*)d_out;                // [BAT,L,A,B] fp32

    // ws: [0, 8.5MB) codes_t | [8.5, 9.0MB) rsw | [9.0MB, +34MB) asw
    unsigned int* codes_t = (unsigned int*)d_ws;                    // 8912896 B
    __bf16* rsw = (__bf16*)((char*)d_ws + 8912896);                 // 524288 B
    __bf16* asw = (__bf16*)((char*)d_ws + 8912896 + 524288);        // 35651584 B

    preswz_kernel<<<NAGRP + NBGRP, 256, 0, stream>>>(qe, de, r, asw, rsw);
    hash_kernel<<<(NXB / NTPB) * NYB, 512, 0, stream>>>(asw, rsw, codes_t);
    simmat_kernel<<<L_ * BAT_ * 8 * 4, 256, 0, stream>>>(codes_t, qtok, dtok, out);
}